// Round 1
// baseline (142.619 us; speedup 1.0000x reference)
//
#include <hip/hip_runtime.h>
#include <math.h>

// Problem constants (from reference):
//   vol: (B=1, C=1, W=96, H=96, D=64) float32, row-major -> vol[(x*96+y)*64+z]
//   out: (B,C,U=96,A=90,V=64) float32 -> out[(u*90+a)*64+v]
//   k[v] = v identically (V=D=64, SV=SD=1), so depth slice index == lane.
namespace {
constexpr int An = 90, Un = 96, Vn = 64, Wn = 96, Hn = 96, Dn = 64;
constexpr int NSTEPS = Hn + Wn + 2; // 194
}

// One wave64 per ray: lane = v (contiguous innermost axis of vol), traversal
// state is wave-uniform -> zero divergence, every load is a coalesced 256B row.
__global__ __launch_bounds__(64)
void siddon_fwd_kernel(const float* __restrict__ vol, float* __restrict__ out)
{
    const int ray = blockIdx.x;       // ray = a*U + u (matches reference reshape)
    const int a   = ray / Un;
    const int u   = ray - a * Un;
    const int v   = threadIdx.x;      // 0..63

    const float EPSf = 1e-12f;
    const float INF  = __builtin_inff();
    const float DIAG = 1.41421356237309514547f; // float(sqrt(2))

    // angles = linspace(0, pi, 90, endpoint=False) in f32: a * (pi/90)
    const float ang = (float)a * (float)(3.14159265358979323846 / 90.0);
    // cos/sin of the f32 angle, computed in f64 then rounded (matches numpy f32 cos to <=1ulp)
    const float dx = (float)cos((double)ang);
    const float dy = (float)sin((double)ang);
    const float uu = (float)u - 47.5f;          // (u - (U-1)/2) * SU
    const float x0 = __fmul_rn(-uu, dy);        // -u*sin
    const float y0 = __fmul_rn( uu, dx);        //  u*cos

    const float xmin = -47.5f, xmax = 47.5f;
    const float ymin = -47.5f, ymax = 47.5f;

    // _t_for in x
    float tx0, tx1;
    {
        const bool par = fabsf(dx) < EPSf;
        const float safe = par ? 1.0f : dx;
        const float t0 = __fdiv_rn(xmin - x0, safe);
        const float t1 = __fdiv_rn(xmax - x0, safe);
        const float lo = fminf(t0, t1), hi = fmaxf(t0, t1);
        const bool inside = (x0 >= xmin) && (x0 <= xmax);
        tx0 = par ? (inside ? -INF : INF) : lo;
        tx1 = par ? (inside ?  INF : -INF) : hi;
    }
    // _t_for in y
    float ty0, ty1;
    {
        const bool par = fabsf(dy) < EPSf;
        const float safe = par ? 1.0f : dy;
        const float t0 = __fdiv_rn(ymin - y0, safe);
        const float t1 = __fdiv_rn(ymax - y0, safe);
        const float lo = fminf(t0, t1), hi = fmaxf(t0, t1);
        const bool inside = (y0 >= ymin) && (y0 <= ymax);
        ty0 = par ? (inside ? -INF : INF) : lo;
        ty1 = par ? (inside ?  INF : -INF) : hi;
    }

    const float t_entry = fmaxf(tx0, ty0);
    const float t_exit  = fminf(tx1, ty1);
    bool  alive = t_entry < t_exit;
    const float te  = alive ? t_entry : 0.0f;
    const float tex = alive ? t_exit  : 0.0f;

    float x = __fadd_rn(x0, __fmul_rn(te, dx));
    float y = __fadd_rn(y0, __fmul_rn(te, dy));
    // i0 = clip(round(xe/SX + 47.5), 0, 95); rintf = round-half-even like jnp.round
    int i = (int)fminf(fmaxf(rintf(__fadd_rn(x, 47.5f)), 0.0f), 95.0f);
    int j = (int)fminf(fmaxf(rintf(__fadd_rn(y, 47.5f)), 0.0f), 95.0f);
    float t = te;

    const float inv_sum = fmaxf(fabsf(dx) + fabsf(dy), EPSf);

    float acc = 0.0f;
    const float* __restrict__ volv = vol + v;

    for (int n = 0; n < NSTEPS; ++n) {
        // valid = alive & (t < tex - EPS); once false it stays false in the
        // reference (state frozen, w=0 emitted), so breaking is equivalent.
        const bool valid = alive && (t < __fadd_rn(tex, -EPSf));
        if (!valid) break;

        const float fi = (float)i, fj = (float)j;
        const float xn = (dx > 0.0f) ? (fi + 0.5f) - 47.5f
                       : (dx < 0.0f) ? (fi - 0.5f) - 47.5f : INF;
        const float yn = (dy > 0.0f) ? (fj + 0.5f) - 47.5f
                       : (dy < 0.0f) ? (fj - 0.5f) - 47.5f : INF;

        const float txc = (fabsf(dx) > EPSf) ? __fdiv_rn(xn - x, dx) : INF;
        const float tyc = (fabsf(dy) > EPSf) ? __fdiv_rn(yn - y, dy) : INF;

        const float dt  = fminf(fminf(txc, tyc), __fadd_rn(tex, -t));
        const float seg = fmaxf(0.0f, __fdiv_rn(__fmul_rn(dt, DIAG), inv_sum));

        // emit (i, j, seg): coalesced 64-lane row load, lane v = depth slice
        acc = fmaf(seg, volv[(i * Hn + j) * Dn], acc);

        const int i_n = i + ((txc <= tyc) ? ((dx > 0.0f) ? 1 : -1) : 0);
        const int j_n = j + ((tyc <= txc) ? ((dy > 0.0f) ? 1 : -1) : 0);
        const bool inb = (i_n >= 0) && (i_n < Wn) && (j_n >= 0) && (j_n < Hn);

        // state update, separate mul/add rounding to match the reference
        x = __fadd_rn(x, __fmul_rn(dx, dt));
        y = __fadd_rn(y, __fmul_rn(dy, dt));
        t = __fadd_rn(t, dt);
        i = i_n;
        j = j_n;
        alive = inb;
    }

    out[(u * An + a) * Vn + v] = acc;
}

extern "C" void kernel_launch(void* const* d_in, const int* in_sizes, int n_in,
                              void* d_out, int out_size, void* d_ws, size_t ws_size,
                              hipStream_t stream) {
    const float* vol = (const float*)d_in[0];
    float* out = (float*)d_out;
    dim3 grid(An * Un);   // 8640 rays, one wave64 each
    dim3 block(64);
    hipLaunchKernelGGL(siddon_fwd_kernel, grid, block, 0, stream, vol, out);
}

// Round 2
// 119.560 us; speedup vs baseline: 1.1929x; 1.1929x over previous
//
#include <hip/hip_runtime.h>
#include <math.h>

// Problem constants (from reference):
//   vol: (B=1, C=1, W=96, H=96, D=64) float32, row-major -> vol[(x*96+y)*64+z]
//   out: (B,C,U=96,A=90,V=64) float32 -> out[(u*90+a)*64+v]
//   k[v] = v identically (V=D=64, SV=SD=1), so depth slice index == lane.
namespace {
constexpr int An = 90, Un = 96, Vn = 64, Wn = 96, Hn = 96, Dn = 64;
constexpr int NRAY = An * Un;       // 8640
constexpr int NSTEPS = Hn + Wn + 2; // 194
}

// ---------------------------------------------------------------------------
// Phase 1: one lane per ray. Each lane runs the full Siddon traversal and
// emits a compact (voxel_row_offset, weight) list + count into workspace.
// This does the wave-uniform trace work ONCE per ray instead of 64x.
// Entry packed as float2: .x = __int_as_float(element offset), .y = weight.
// ---------------------------------------------------------------------------
__global__ __launch_bounds__(64)
void trace_kernel(float2* __restrict__ ents, int* __restrict__ counts)
{
    const int ray = blockIdx.x * 64 + threadIdx.x;  // 0..8639 = a*96 + u
    if (ray >= NRAY) return;
    const int a = ray / Un;
    const int u = ray - a * Un;

    const float EPSf = 1e-12f;
    const float INF  = __builtin_inff();
    const float DIAG = 1.41421356237309514547f;

    const float ang = (float)a * (float)(3.14159265358979323846 / 90.0);
    const float dx = (float)cos((double)ang);
    const float dy = (float)sin((double)ang);
    const float uu = (float)u - 47.5f;
    const float x0 = __fmul_rn(-uu, dy);
    const float y0 = __fmul_rn( uu, dx);

    const float xmin = -47.5f, xmax = 47.5f;
    const float ymin = -47.5f, ymax = 47.5f;

    float tx0, tx1;
    {
        const bool par = fabsf(dx) < EPSf;
        const float safe = par ? 1.0f : dx;
        const float t0 = __fdiv_rn(xmin - x0, safe);
        const float t1 = __fdiv_rn(xmax - x0, safe);
        const float lo = fminf(t0, t1), hi = fmaxf(t0, t1);
        const bool inside = (x0 >= xmin) && (x0 <= xmax);
        tx0 = par ? (inside ? -INF : INF) : lo;
        tx1 = par ? (inside ?  INF : -INF) : hi;
    }
    float ty0, ty1;
    {
        const bool par = fabsf(dy) < EPSf;
        const float safe = par ? 1.0f : dy;
        const float t0 = __fdiv_rn(ymin - y0, safe);
        const float t1 = __fdiv_rn(ymax - y0, safe);
        const float lo = fminf(t0, t1), hi = fmaxf(t0, t1);
        const bool inside = (y0 >= ymin) && (y0 <= ymax);
        ty0 = par ? (inside ? -INF : INF) : lo;
        ty1 = par ? (inside ?  INF : -INF) : hi;
    }

    const float t_entry = fmaxf(tx0, ty0);
    const float t_exit  = fminf(tx1, ty1);
    bool  alive = t_entry < t_exit;
    const float te  = alive ? t_entry : 0.0f;
    const float tex = alive ? t_exit  : 0.0f;

    float x = __fadd_rn(x0, __fmul_rn(te, dx));
    float y = __fadd_rn(y0, __fmul_rn(te, dy));
    int i = (int)fminf(fmaxf(rintf(__fadd_rn(x, 47.5f)), 0.0f), 95.0f);
    int j = (int)fminf(fmaxf(rintf(__fadd_rn(y, 47.5f)), 0.0f), 95.0f);
    float t = te;

    const bool okx = fabsf(dx) > EPSf;
    const bool oky = fabsf(dy) > EPSf;
    // reciprocal-mul instead of per-step IEEE div: <=2 ulp vs reference; only
    // matters at exact corner ties whose segments are ~zero-length.
    const float inv_dx = okx ? __fdiv_rn(1.0f, dx) : 0.0f;
    const float inv_dy = oky ? __fdiv_rn(1.0f, dy) : 0.0f;
    const float wscale = __fdiv_rn(DIAG, fmaxf(fabsf(dx) + fabsf(dy), EPSf));
    const float tex_m_eps = __fadd_rn(tex, -EPSf);

    float2* __restrict__ my = ents + (size_t)ray * NSTEPS;
    int n = 0;

    for (int step = 0; step < NSTEPS; ++step) {
        const bool valid = alive && (t < tex_m_eps);
        if (!__ballot(valid)) break;   // all lanes in wave done
        if (valid) {
            const float fi = (float)i, fj = (float)j;
            const float xn = (dx > 0.0f) ? (fi + 0.5f) - 47.5f
                           : (dx < 0.0f) ? (fi - 0.5f) - 47.5f : INF;
            const float yn = (dy > 0.0f) ? (fj + 0.5f) - 47.5f
                           : (dy < 0.0f) ? (fj - 0.5f) - 47.5f : INF;
            const float txc = okx ? __fmul_rn(xn - x, inv_dx) : INF;
            const float tyc = oky ? __fmul_rn(yn - y, inv_dy) : INF;
            const float dt  = fminf(fminf(txc, tyc), __fadd_rn(tex, -t));
            const float seg = fmaxf(0.0f, __fmul_rn(dt, wscale));

            float2 e;
            e.x = __int_as_float((i * Hn + j) * Dn);  // element offset into vol
            e.y = seg;
            my[n] = e;
            ++n;

            const int i_n = i + ((txc <= tyc) ? ((dx > 0.0f) ? 1 : -1) : 0);
            const int j_n = j + ((tyc <= txc) ? ((dy > 0.0f) ? 1 : -1) : 0);
            const bool inb = (i_n >= 0) && (i_n < Wn) && (j_n >= 0) && (j_n < Hn);
            x = __fadd_rn(x, __fmul_rn(dx, dt));
            y = __fadd_rn(y, __fmul_rn(dy, dt));
            t = __fadd_rn(t, dt);
            i = i_n; j = j_n;
            alive = inb;
        }
    }
    counts[ray] = n;
}

// ---------------------------------------------------------------------------
// Phase 2: one wave per ray (lane = v, contiguous depth axis), 4 rays/block.
// Inner loop: broadcast entry load + coalesced 256B vol row load + fmaf.
// ---------------------------------------------------------------------------
__global__ __launch_bounds__(256)
void gather_kernel(const float* __restrict__ vol,
                   const float2* __restrict__ ents,
                   const int* __restrict__ counts,
                   float* __restrict__ out)
{
    const int wid = threadIdx.x >> 6;                 // wave in block 0..3
    const int ray = (blockIdx.x << 2) + wid;          // a*96 + u
    const int v   = threadIdx.x & 63;

    const int cnt = counts[ray];
    const float2* __restrict__ e = ents + (size_t)ray * NSTEPS;
    const float* __restrict__ volv = vol + v;

    float acc = 0.0f;
    int n = 0;
    for (; n + 4 <= cnt; n += 4) {
        const float2 e0 = e[n + 0];
        const float2 e1 = e[n + 1];
        const float2 e2 = e[n + 2];
        const float2 e3 = e[n + 3];
        acc = fmaf(e0.y, volv[__float_as_int(e0.x)], acc);
        acc = fmaf(e1.y, volv[__float_as_int(e1.x)], acc);
        acc = fmaf(e2.y, volv[__float_as_int(e2.x)], acc);
        acc = fmaf(e3.y, volv[__float_as_int(e3.x)], acc);
    }
    for (; n < cnt; ++n) {
        const float2 e0 = e[n];
        acc = fmaf(e0.y, volv[__float_as_int(e0.x)], acc);
    }

    const int a = ray / Un;
    const int u = ray - a * Un;
    out[(u * An + a) * Vn + v] = acc;
}

// ---------------------------------------------------------------------------
// Fallback: the proven single-kernel version (used if ws_size is too small).
// ---------------------------------------------------------------------------
__global__ __launch_bounds__(64)
void siddon_fwd_kernel(const float* __restrict__ vol, float* __restrict__ out)
{
    const int ray = blockIdx.x;
    const int a   = ray / Un;
    const int u   = ray - a * Un;
    const int v   = threadIdx.x;

    const float EPSf = 1e-12f;
    const float INF  = __builtin_inff();
    const float DIAG = 1.41421356237309514547f;

    const float ang = (float)a * (float)(3.14159265358979323846 / 90.0);
    const float dx = (float)cos((double)ang);
    const float dy = (float)sin((double)ang);
    const float uu = (float)u - 47.5f;
    const float x0 = __fmul_rn(-uu, dy);
    const float y0 = __fmul_rn( uu, dx);

    const float xmin = -47.5f, xmax = 47.5f;
    const float ymin = -47.5f, ymax = 47.5f;

    float tx0, tx1;
    {
        const bool par = fabsf(dx) < EPSf;
        const float safe = par ? 1.0f : dx;
        const float t0 = __fdiv_rn(xmin - x0, safe);
        const float t1 = __fdiv_rn(xmax - x0, safe);
        const float lo = fminf(t0, t1), hi = fmaxf(t0, t1);
        const bool inside = (x0 >= xmin) && (x0 <= xmax);
        tx0 = par ? (inside ? -INF : INF) : lo;
        tx1 = par ? (inside ?  INF : -INF) : hi;
    }
    float ty0, ty1;
    {
        const bool par = fabsf(dy) < EPSf;
        const float safe = par ? 1.0f : dy;
        const float t0 = __fdiv_rn(ymin - y0, safe);
        const float t1 = __fdiv_rn(ymax - y0, safe);
        const float lo = fminf(t0, t1), hi = fmaxf(t0, t1);
        const bool inside = (y0 >= ymin) && (y0 <= ymax);
        ty0 = par ? (inside ? -INF : INF) : lo;
        ty1 = par ? (inside ?  INF : -INF) : hi;
    }

    const float t_entry = fmaxf(tx0, ty0);
    const float t_exit  = fminf(tx1, ty1);
    bool  alive = t_entry < t_exit;
    const float te  = alive ? t_entry : 0.0f;
    const float tex = alive ? t_exit  : 0.0f;

    float x = __fadd_rn(x0, __fmul_rn(te, dx));
    float y = __fadd_rn(y0, __fmul_rn(te, dy));
    int i = (int)fminf(fmaxf(rintf(__fadd_rn(x, 47.5f)), 0.0f), 95.0f);
    int j = (int)fminf(fmaxf(rintf(__fadd_rn(y, 47.5f)), 0.0f), 95.0f);
    float t = te;

    const float inv_sum = fmaxf(fabsf(dx) + fabsf(dy), EPSf);

    float acc = 0.0f;
    const float* __restrict__ volv = vol + v;

    for (int n = 0; n < NSTEPS; ++n) {
        const bool valid = alive && (t < __fadd_rn(tex, -EPSf));
        if (!valid) break;

        const float fi = (float)i, fj = (float)j;
        const float xn = (dx > 0.0f) ? (fi + 0.5f) - 47.5f
                       : (dx < 0.0f) ? (fi - 0.5f) - 47.5f : INF;
        const float yn = (dy > 0.0f) ? (fj + 0.5f) - 47.5f
                       : (dy < 0.0f) ? (fj - 0.5f) - 47.5f : INF;
        const float txc = (fabsf(dx) > EPSf) ? __fdiv_rn(xn - x, dx) : INF;
        const float tyc = (fabsf(dy) > EPSf) ? __fdiv_rn(yn - y, dy) : INF;
        const float dt  = fminf(fminf(txc, tyc), __fadd_rn(tex, -t));
        const float seg = fmaxf(0.0f, __fdiv_rn(__fmul_rn(dt, DIAG), inv_sum));

        acc = fmaf(seg, volv[(i * Hn + j) * Dn], acc);

        const int i_n = i + ((txc <= tyc) ? ((dx > 0.0f) ? 1 : -1) : 0);
        const int j_n = j + ((tyc <= txc) ? ((dy > 0.0f) ? 1 : -1) : 0);
        const bool inb = (i_n >= 0) && (i_n < Wn) && (j_n >= 0) && (j_n < Hn);
        x = __fadd_rn(x, __fmul_rn(dx, dt));
        y = __fadd_rn(y, __fmul_rn(dy, dt));
        t = __fadd_rn(t, dt);
        i = i_n; j = j_n;
        alive = inb;
    }

    out[(u * An + a) * Vn + v] = acc;
}

extern "C" void kernel_launch(void* const* d_in, const int* in_sizes, int n_in,
                              void* d_out, int out_size, void* d_ws, size_t ws_size,
                              hipStream_t stream) {
    const float* vol = (const float*)d_in[0];
    float* out = (float*)d_out;

    const size_t ents_bytes  = (size_t)NRAY * NSTEPS * sizeof(float2); // 13.4 MB
    const size_t counts_bytes = (size_t)NRAY * sizeof(int);
    if (ws_size >= ents_bytes + counts_bytes) {
        float2* ents  = (float2*)d_ws;
        int*    counts = (int*)((char*)d_ws + ents_bytes);
        hipLaunchKernelGGL(trace_kernel, dim3((NRAY + 63) / 64), dim3(64), 0, stream,
                           ents, counts);
        hipLaunchKernelGGL(gather_kernel, dim3(NRAY / 4), dim3(256), 0, stream,
                           vol, ents, counts, out);
    } else {
        hipLaunchKernelGGL(siddon_fwd_kernel, dim3(NRAY), dim3(64), 0, stream,
                           vol, out);
    }
}